// Round 1
// baseline (166.639 us; speedup 1.0000x reference)
//
#include <hip/hip_runtime.h>
#include <math.h>

#define B_SZ 512
#define K_SZ 8
#define L_SZ 50
#define DLLM 768
#define H_SZ 128
#define N_ITEM 100000
#define DIV_TRADEOFF 0.1f

// Kernel 1: one block per (b,k). Gather item embeddings with time-decay
// weights into LDS, then project 768 -> 128 with W (+ bias * sum_w).
__global__ __launch_bounds__(256) void k_embed(
    const int* __restrict__ preds,        // [B,K,L]
    const float* __restrict__ item,       // [N_ITEM+1, 768]
    const float* __restrict__ W,          // [768, 128]
    const float* __restrict__ bproj,      // [128]
    float* __restrict__ emb)              // [B*K, 128] out
{
    const int bk  = blockIdx.x;
    const int tid = threadIdx.x;

    __shared__ float wf[DLLM];
    __shared__ float part[256];

    const int* p = preds + (size_t)bk * L_SZ;
    float a0 = 0.f, a1 = 0.f, a2 = 0.f;
    for (int l = 0; l < L_SZ; ++l) {
        const int id = p[l];
        if (id > 0 && id <= N_ITEM) {
            const float w = 1.0f / log2f((float)(l + 2));
            const float* row = item + (size_t)id * DLLM;
            a0 += w * row[tid];
            a1 += w * row[tid + 256];
            a2 += w * row[tid + 512];
        }
    }
    wf[tid]       = a0;
    wf[tid + 256] = a1;
    wf[tid + 512] = a2;
    __syncthreads();

    // Projection: 256 threads = 128 h-columns x 2 d-halves of 384.
    const int h    = tid & (H_SZ - 1);
    const int half = tid >> 7;
    const float* Wc = W + h;
    float s = 0.f;
    const int d0 = half * 384;
    #pragma unroll 4
    for (int d = d0; d < d0 + 384; ++d) {
        s += wf[d] * Wc[(size_t)d * H_SZ];
    }
    part[tid] = s;
    __syncthreads();

    if (tid < H_SZ) {
        float sumw = 0.f;
        for (int l = 0; l < L_SZ; ++l) sumw += 1.0f / log2f((float)(l + 2));
        emb[(size_t)bk * H_SZ + tid] = part[tid] + part[tid + H_SZ] + bproj[tid] * sumw;
    }
}

// Kernel 2: one block per b. Softmax over K, pairwise loss, gram diversity.
__global__ __launch_bounds__(256) void k_loss(
    const int* __restrict__ user_id,      // [B]
    const float* __restrict__ pref_in,    // [B,128]
    const float* __restrict__ pos_label,  // [B,K]
    const float* __restrict__ neg_label,  // [B,K]
    const float* __restrict__ user_emb,   // [50000,128]
    const float* __restrict__ emb,        // [B*K,128]
    float* __restrict__ out)              // [1]
{
    const int b   = blockIdx.x;
    const int tid = threadIdx.x;

    __shared__ float pref[H_SZ];
    __shared__ float e[K_SZ][H_SZ];
    __shared__ float sdot[K_SZ];
    __shared__ float wg[K_SZ];
    __shared__ float lossb_s;

    if (tid < H_SZ) {
        const int uid = user_id[b];
        pref[tid] = pref_in[(size_t)b * H_SZ + tid]
                  + user_emb[(size_t)uid * H_SZ + tid];
    }
    const float* eb = emb + (size_t)b * K_SZ * H_SZ;
    #pragma unroll
    for (int i = 0; i < 4; ++i) {
        const int idx = tid * 4 + i;           // 0..1023
        e[idx >> 7][idx & (H_SZ - 1)] = eb[idx];
    }
    __syncthreads();

    // wgts_org[k] = dot(e[k], pref): 8 groups of 32 lanes.
    {
        const int k    = tid >> 5;
        const int lane = tid & 31;
        float s = e[k][lane]      * pref[lane]
                + e[k][lane + 32] * pref[lane + 32]
                + e[k][lane + 64] * pref[lane + 64]
                + e[k][lane + 96] * pref[lane + 96];
        #pragma unroll
        for (int m = 16; m >= 1; m >>= 1) s += __shfl_xor(s, m, 64);
        if (lane == 0) sdot[k] = s;
    }
    __syncthreads();

    if (tid == 0) {
        // softmax over K=8
        float mx = sdot[0];
        #pragma unroll
        for (int k = 1; k < K_SZ; ++k) mx = fmaxf(mx, sdot[k]);
        float sum = 0.f;
        float ex[K_SZ];
        #pragma unroll
        for (int k = 0; k < K_SZ; ++k) { ex[k] = expf(sdot[k] - mx); sum += ex[k]; }
        float ps = 0.f, ns = 0.f;
        #pragma unroll
        for (int k = 0; k < K_SZ; ++k) {
            const float w = ex[k] / sum;
            wg[k] = w;
            ps += pos_label[(size_t)b * K_SZ + k] * w;
            ns += neg_label[(size_t)b * K_SZ + k] * w;
        }
        const float x = ps - ns;
        // -log_sigmoid(x) = softplus(-x), numerically stable
        lossb_s = fmaxf(-x, 0.f) + log1pf(expf(-fabsf(x)));
    }
    __syncthreads();

    // diversity: sum over i!=j of dot(e_i,e_j)^2 * (w_i + w_j)
    if (tid < 64) {
        const int i = tid >> 3;
        const int j = tid & 7;
        float g = 0.f;
        for (int h = 0; h < H_SZ; ++h) g += e[i][h] * e[j][h];
        float v = (i != j) ? (g * g * (wg[i] + wg[j])) : 0.f;
        #pragma unroll
        for (int m = 32; m >= 1; m >>= 1) v += __shfl_xor(v, m, 64);
        if (tid == 0) {
            const float mean_div = v / (float)(B_SZ * K_SZ * K_SZ);
            atomicAdd(out, lossb_s + DIV_TRADEOFF * mean_div);
        }
    }
}

extern "C" void kernel_launch(void* const* d_in, const int* in_sizes, int n_in,
                              void* d_out, int out_size, void* d_ws, size_t ws_size,
                              hipStream_t stream) {
    const int*   user_id   = (const int*)  d_in[0];
    const int*   preds     = (const int*)  d_in[1];
    const float* pref_in   = (const float*)d_in[2];
    const float* pos_label = (const float*)d_in[3];
    const float* neg_label = (const float*)d_in[4];
    const float* user_emb  = (const float*)d_in[5];
    const float* item_emb  = (const float*)d_in[6];
    const float* W_proj    = (const float*)d_in[7];
    const float* b_proj    = (const float*)d_in[8];

    float* out = (float*)d_out;
    float* emb = (float*)d_ws;   // [B*K, 128] f32 = 2 MB scratch

    // zero the scalar output every launch (graph replays don't re-poison)
    hipMemsetAsync(out, 0, sizeof(float), stream);

    k_embed<<<B_SZ * K_SZ, 256, 0, stream>>>(preds, item_emb, W_proj, b_proj, emb);
    k_loss<<<B_SZ, 256, 0, stream>>>(user_id, pref_in, pos_label, neg_label,
                                     user_emb, emb, out);
}

// Round 2
// 145.326 us; speedup vs baseline: 1.1467x; 1.1467x over previous
//
#include <hip/hip_runtime.h>
#include <math.h>

#define B_SZ 512
#define K_SZ 8
#define L_SZ 50
#define DLLM 768
#define H_SZ 128
#define N_ITEM 100000
#define DIV_TRADEOFF 0.1f

// ---------------- Kernel 1: gather + time-decay sum -> wf[B*K, 768] --------
// One block per (b,k). 192 threads; each owns one float4 of the 768-d row.
// Branchless masked gather with an explicit depth-8 prefetch pipeline.
__global__ __launch_bounds__(192) void k_gather(
    const int* __restrict__ preds,        // [B,K,L]
    const float* __restrict__ item,       // [N_ITEM+1, 768]
    float* __restrict__ wf)               // [B*K, 768] out
{
    const int bk  = blockIdx.x;
    const int tid = threadIdx.x;          // 0..191

    __shared__ int   sid[L_SZ];
    __shared__ float swt[L_SZ];
    if (tid < L_SZ) {
        const int id = preds[(size_t)bk * L_SZ + tid];
        const bool v = (id > 0) && (id <= N_ITEM);
        sid[tid] = v ? id : 0;                                // row 0 is real, L2-hot
        swt[tid] = v ? (1.0f / log2f((float)(tid + 2))) : 0.0f;
    }
    __syncthreads();

    const size_t col = (size_t)tid * 4;
    float4 acc = make_float4(0.f, 0.f, 0.f, 0.f);

    constexpr int PF = 8;                 // 8 float4 in flight = 32 VGPR
    float4 buf[PF];
    #pragma unroll
    for (int p = 0; p < PF; ++p)
        buf[p] = *(const float4*)(item + (size_t)sid[p] * DLLM + col);

    #pragma unroll
    for (int l = 0; l < L_SZ; ++l) {      // full unroll -> static buf indices
        const float4 v = buf[l % PF];
        if (l + PF < L_SZ)
            buf[l % PF] = *(const float4*)(item + (size_t)sid[l + PF] * DLLM + col);
        const float w = swt[l];
        acc.x += w * v.x;
        acc.y += w * v.y;
        acc.z += w * v.z;
        acc.w += w * v.w;
    }
    *(float4*)(wf + (size_t)bk * DLLM + col) = acc;
}

// ------------- Kernel 2: projection + softmax + loss, one block per b -------
__global__ __launch_bounds__(256) void k_projloss(
    const float* __restrict__ wf,         // [B*K, 768]
    const float* __restrict__ W,          // [768, 128]
    const float* __restrict__ bproj,      // [128]
    const int* __restrict__ user_id,      // [B]
    const float* __restrict__ pref_in,    // [B,128]
    const float* __restrict__ pos_label,  // [B,K]
    const float* __restrict__ neg_label,  // [B,K]
    const float* __restrict__ user_emb,   // [50000,128]
    float* __restrict__ out)              // [1]
{
    const int b   = blockIdx.x;
    const int tid = threadIdx.x;
    const int c   = tid & (H_SZ - 1);     // 0..127 output column
    const int rg  = tid >> 7;             // 0/1 row group

    __shared__ float A[K_SZ][H_SZ];       // staged wf k-chunk (4 KB)
    __shared__ float e[K_SZ][H_SZ + 1];   // padded: breaks gram bank conflicts
    __shared__ float pref[H_SZ];
    __shared__ float sdot[K_SZ];
    __shared__ float wg[K_SZ];
    __shared__ float lossb_s;

    float acc[4] = {0.f, 0.f, 0.f, 0.f};  // rows rg, rg+2, rg+4, rg+6
    const size_t rowbase = (size_t)b * K_SZ;

    for (int kb = 0; kb < DLLM; kb += H_SZ) {   // 6 chunks of 128 k
        __syncthreads();
        {   // stage A[8][128]: 256 float4 slots, one per thread
            const int r  = tid >> 5;
            const int kk = (tid & 31) * 4;
            *(float4*)&A[r][kk] =
                *(const float4*)(wf + (rowbase + r) * DLLM + kb + kk);
        }
        __syncthreads();

        #pragma unroll 4
        for (int k = 0; k < H_SZ; k += 4) {
            const float4 a0 = *(const float4*)&A[rg    ][k];  // LDS broadcast
            const float4 a1 = *(const float4*)&A[rg + 2][k];
            const float4 a2 = *(const float4*)&A[rg + 4][k];
            const float4 a3 = *(const float4*)&A[rg + 6][k];
            const float* Wp = W + (size_t)(kb + k) * H_SZ + c;
            const float w0 = Wp[0];
            const float w1 = Wp[H_SZ];
            const float w2 = Wp[2 * H_SZ];
            const float w3 = Wp[3 * H_SZ];
            acc[0] += a0.x * w0 + a0.y * w1 + a0.z * w2 + a0.w * w3;
            acc[1] += a1.x * w0 + a1.y * w1 + a1.z * w2 + a1.w * w3;
            acc[2] += a2.x * w0 + a2.y * w1 + a2.z * w2 + a2.w * w3;
            acc[3] += a3.x * w0 + a3.y * w1 + a3.z * w2 + a3.w * w3;
        }
    }

    // bias applies everywhere (matches nn.Linear on zeroed rows): b * sum(w_l)
    float sumw = 0.f;
    #pragma unroll
    for (int l = 0; l < L_SZ; ++l) sumw += 1.0f / log2f((float)(l + 2));
    const float bterm = bproj[c] * sumw;
    #pragma unroll
    for (int ri = 0; ri < 4; ++ri) e[rg + 2 * ri][c] = acc[ri] + bterm;

    if (tid < H_SZ) {
        const int uid = user_id[b];
        pref[tid] = pref_in[(size_t)b * H_SZ + tid]
                  + user_emb[(size_t)uid * H_SZ + tid];
    }
    __syncthreads();

    // wgts_org[k] = dot(e[k], pref): 8 groups of 32 lanes
    {
        const int k    = tid >> 5;
        const int lane = tid & 31;
        float s = e[k][lane]      * pref[lane]
                + e[k][lane + 32] * pref[lane + 32]
                + e[k][lane + 64] * pref[lane + 64]
                + e[k][lane + 96] * pref[lane + 96];
        #pragma unroll
        for (int m = 16; m >= 1; m >>= 1) s += __shfl_xor(s, m, 64);
        if (lane == 0) sdot[k] = s;
    }
    __syncthreads();

    if (tid == 0) {
        float mx = sdot[0];
        #pragma unroll
        for (int k = 1; k < K_SZ; ++k) mx = fmaxf(mx, sdot[k]);
        float sum = 0.f;
        float ex[K_SZ];
        #pragma unroll
        for (int k = 0; k < K_SZ; ++k) { ex[k] = expf(sdot[k] - mx); sum += ex[k]; }
        float ps = 0.f, ns = 0.f;
        #pragma unroll
        for (int k = 0; k < K_SZ; ++k) {
            const float w = ex[k] / sum;
            wg[k] = w;
            ps += pos_label[(size_t)b * K_SZ + k] * w;
            ns += neg_label[(size_t)b * K_SZ + k] * w;
        }
        const float x = ps - ns;
        lossb_s = fmaxf(-x, 0.f) + log1pf(expf(-fabsf(x)));   // softplus(-x)
    }
    __syncthreads();

    // diversity: sum_{i!=j} dot(e_i,e_j)^2 * (w_i + w_j)
    if (tid < 64) {
        const int i = tid >> 3;
        const int j = tid & 7;
        float g = 0.f;
        for (int h = 0; h < H_SZ; ++h) g += e[i][h] * e[j][h];
        float v = (i != j) ? (g * g * (wg[i] + wg[j])) : 0.f;
        #pragma unroll
        for (int m = 32; m >= 1; m >>= 1) v += __shfl_xor(v, m, 64);
        if (tid == 0) {
            const float mean_div = v / (float)(B_SZ * K_SZ * K_SZ);
            atomicAdd(out, lossb_s + DIV_TRADEOFF * mean_div);
        }
    }
}

// ---------------- Fallback path (round-1 kernels) if ws too small -----------
__global__ __launch_bounds__(256) void k_embed_fb(
    const int* __restrict__ preds, const float* __restrict__ item,
    const float* __restrict__ W, const float* __restrict__ bproj,
    float* __restrict__ emb)
{
    const int bk  = blockIdx.x;
    const int tid = threadIdx.x;
    __shared__ float wfs[DLLM];
    __shared__ float part[256];
    const int* p = preds + (size_t)bk * L_SZ;
    float a0 = 0.f, a1 = 0.f, a2 = 0.f;
    for (int l = 0; l < L_SZ; ++l) {
        const int id = p[l];
        if (id > 0 && id <= N_ITEM) {
            const float w = 1.0f / log2f((float)(l + 2));
            const float* row = item + (size_t)id * DLLM;
            a0 += w * row[tid];
            a1 += w * row[tid + 256];
            a2 += w * row[tid + 512];
        }
    }
    wfs[tid] = a0; wfs[tid + 256] = a1; wfs[tid + 512] = a2;
    __syncthreads();
    const int h = tid & (H_SZ - 1);
    const int half = tid >> 7;
    const float* Wc = W + h;
    float s = 0.f;
    const int d0 = half * 384;
    #pragma unroll 4
    for (int d = d0; d < d0 + 384; ++d) s += wfs[d] * Wc[(size_t)d * H_SZ];
    part[tid] = s;
    __syncthreads();
    if (tid < H_SZ) {
        float sumw = 0.f;
        for (int l = 0; l < L_SZ; ++l) sumw += 1.0f / log2f((float)(l + 2));
        emb[(size_t)bk * H_SZ + tid] = part[tid] + part[tid + H_SZ] + bproj[tid] * sumw;
    }
}

__global__ __launch_bounds__(256) void k_loss_fb(
    const int* __restrict__ user_id, const float* __restrict__ pref_in,
    const float* __restrict__ pos_label, const float* __restrict__ neg_label,
    const float* __restrict__ user_emb, const float* __restrict__ emb,
    float* __restrict__ out)
{
    const int b = blockIdx.x;
    const int tid = threadIdx.x;
    __shared__ float pref[H_SZ];
    __shared__ float e[K_SZ][H_SZ + 1];
    __shared__ float sdot[K_SZ];
    __shared__ float wg[K_SZ];
    __shared__ float lossb_s;
    if (tid < H_SZ) {
        const int uid = user_id[b];
        pref[tid] = pref_in[(size_t)b * H_SZ + tid] + user_emb[(size_t)uid * H_SZ + tid];
    }
    const float* eb = emb + (size_t)b * K_SZ * H_SZ;
    #pragma unroll
    for (int i = 0; i < 4; ++i) {
        const int idx = tid * 4 + i;
        e[idx >> 7][idx & (H_SZ - 1)] = eb[idx];
    }
    __syncthreads();
    {
        const int k = tid >> 5;
        const int lane = tid & 31;
        float s = e[k][lane] * pref[lane] + e[k][lane + 32] * pref[lane + 32]
                + e[k][lane + 64] * pref[lane + 64] + e[k][lane + 96] * pref[lane + 96];
        #pragma unroll
        for (int m = 16; m >= 1; m >>= 1) s += __shfl_xor(s, m, 64);
        if (lane == 0) sdot[k] = s;
    }
    __syncthreads();
    if (tid == 0) {
        float mx = sdot[0];
        #pragma unroll
        for (int k = 1; k < K_SZ; ++k) mx = fmaxf(mx, sdot[k]);
        float sum = 0.f; float ex[K_SZ];
        #pragma unroll
        for (int k = 0; k < K_SZ; ++k) { ex[k] = expf(sdot[k] - mx); sum += ex[k]; }
        float ps = 0.f, ns = 0.f;
        #pragma unroll
        for (int k = 0; k < K_SZ; ++k) {
            const float w = ex[k] / sum;
            wg[k] = w;
            ps += pos_label[(size_t)b * K_SZ + k] * w;
            ns += neg_label[(size_t)b * K_SZ + k] * w;
        }
        const float x = ps - ns;
        lossb_s = fmaxf(-x, 0.f) + log1pf(expf(-fabsf(x)));
    }
    __syncthreads();
    if (tid < 64) {
        const int i = tid >> 3;
        const int j = tid & 7;
        float g = 0.f;
        for (int h = 0; h < H_SZ; ++h) g += e[i][h] * e[j][h];
        float v = (i != j) ? (g * g * (wg[i] + wg[j])) : 0.f;
        #pragma unroll
        for (int m = 32; m >= 1; m >>= 1) v += __shfl_xor(v, m, 64);
        if (tid == 0) {
            const float mean_div = v / (float)(B_SZ * K_SZ * K_SZ);
            atomicAdd(out, lossb_s + DIV_TRADEOFF * mean_div);
        }
    }
}

extern "C" void kernel_launch(void* const* d_in, const int* in_sizes, int n_in,
                              void* d_out, int out_size, void* d_ws, size_t ws_size,
                              hipStream_t stream) {
    const int*   user_id   = (const int*)  d_in[0];
    const int*   preds     = (const int*)  d_in[1];
    const float* pref_in   = (const float*)d_in[2];
    const float* pos_label = (const float*)d_in[3];
    const float* neg_label = (const float*)d_in[4];
    const float* user_emb  = (const float*)d_in[5];
    const float* item_emb  = (const float*)d_in[6];
    const float* W_proj    = (const float*)d_in[7];
    const float* b_proj    = (const float*)d_in[8];

    float* out = (float*)d_out;
    hipMemsetAsync(out, 0, sizeof(float), stream);

    const size_t wf_bytes = (size_t)B_SZ * K_SZ * DLLM * sizeof(float); // 12.6 MB

    if (ws_size >= wf_bytes) {
        float* wf = (float*)d_ws;
        k_gather<<<B_SZ * K_SZ, 192, 0, stream>>>(preds, item_emb, wf);
        k_projloss<<<B_SZ, 256, 0, stream>>>(wf, W_proj, b_proj, user_id, pref_in,
                                             pos_label, neg_label, user_emb, out);
    } else {
        float* emb = (float*)d_ws;   // 2 MB
        k_embed_fb<<<B_SZ * K_SZ, 256, 0, stream>>>(preds, item_emb, W_proj, b_proj, emb);
        k_loss_fb<<<B_SZ, 256, 0, stream>>>(user_id, pref_in, pos_label, neg_label,
                                            user_emb, emb, out);
    }
}

// Round 3
// 140.870 us; speedup vs baseline: 1.1829x; 1.0316x over previous
//
#include <hip/hip_runtime.h>
#include <math.h>

#define B_SZ 512
#define K_SZ 8
#define L_SZ 50
#define DLLM 768
#define H_SZ 128
#define N_ITEM 100000
#define DIV_TRADEOFF 0.1f

// ---------------- Kernel 1: gather + time-decay sum -> wf[B*K, 768] --------
// One block per (b,k), 192 threads (each owns one float4 column slice).
// ids are read as wave-uniform loads (scalarize to s_load); weights are
// compile-time constants (log2f of literals folds). Hot loop is a pure
// global_load_dwordx4 + v_fma stream with an 8-deep register ring.
__global__ __launch_bounds__(192) void k_gather(
    const int* __restrict__ preds,        // [B,K,L]
    const float* __restrict__ item,       // [N_ITEM+1, 768]
    float* __restrict__ wf,               // [B*K, 768] out
    float* __restrict__ out)              // [1] zeroed here (graph has no memset)
{
    const int bk  = blockIdx.x;
    const int tid = threadIdx.x;          // 0..191
    if (bk == 0 && tid == 0) out[0] = 0.0f;

    const int* __restrict__ p = preds + (size_t)bk * L_SZ;   // wave-uniform
    const float* __restrict__ ibase = item + (size_t)tid * 4; // per-lane col

    float4 acc = make_float4(0.f, 0.f, 0.f, 0.f);

    constexpr int PF = 8;                 // 8 float4 in flight = 32 VGPR
    float4 buf[PF];
    float  wgt[PF];

    #pragma unroll
    for (int i = 0; i < PF; ++i) {
        const int id = p[i];                             // scalar load
        const bool v = (id > 0) && (id <= N_ITEM);
        wgt[i] = v ? (1.0f / log2f((float)(i + 2))) : 0.0f;   // const-folded
        buf[i] = *(const float4*)(ibase + (size_t)(v ? id : 0) * DLLM);
    }

    #pragma unroll
    for (int l = 0; l < L_SZ; ++l) {      // full unroll -> static ring indices
        const int s = l % PF;
        const float4 v4 = buf[s];
        const float  w  = wgt[s];
        if (l + PF < L_SZ) {
            const int id = p[l + PF];                    // scalar load
            const bool v = (id > 0) && (id <= N_ITEM);
            wgt[s] = v ? (1.0f / log2f((float)(l + PF + 2))) : 0.0f;
            buf[s] = *(const float4*)(ibase + (size_t)(v ? id : 0) * DLLM);
        }
        acc.x += w * v4.x;
        acc.y += w * v4.y;
        acc.z += w * v4.z;
        acc.w += w * v4.w;
    }
    *(float4*)(wf + (size_t)bk * DLLM + (size_t)tid * 4) = acc;
}

// ------------- Kernel 2: projection + softmax + loss, one block per b -------
__global__ __launch_bounds__(256) void k_projloss(
    const float* __restrict__ wf,         // [B*K, 768]
    const float* __restrict__ W,          // [768, 128]
    const float* __restrict__ bproj,      // [128]
    const int* __restrict__ user_id,      // [B]
    const float* __restrict__ pref_in,    // [B,128]
    const float* __restrict__ pos_label,  // [B,K]
    const float* __restrict__ neg_label,  // [B,K]
    const float* __restrict__ user_emb,   // [50000,128]
    float* __restrict__ out)              // [1]
{
    const int b   = blockIdx.x;
    const int tid = threadIdx.x;
    const int c   = tid & (H_SZ - 1);     // 0..127 output column
    const int rg  = tid >> 7;             // 0/1 row group

    __shared__ float A[K_SZ][H_SZ];       // staged wf k-chunk (4 KB)
    __shared__ float e[K_SZ][H_SZ + 1];   // padded: breaks gram bank conflicts
    __shared__ float pref[H_SZ];
    __shared__ float sdot[K_SZ];
    __shared__ float wg[K_SZ];
    __shared__ float lossb_s;

    float acc[4] = {0.f, 0.f, 0.f, 0.f};  // rows rg, rg+2, rg+4, rg+6
    const size_t rowbase = (size_t)b * K_SZ;

    for (int kb = 0; kb < DLLM; kb += H_SZ) {   // 6 chunks of 128 k
        __syncthreads();
        {   // stage A[8][128]: 256 float4 slots, one per thread
            const int r  = tid >> 5;
            const int kk = (tid & 31) * 4;
            *(float4*)&A[r][kk] =
                *(const float4*)(wf + (rowbase + r) * DLLM + kb + kk);
        }
        __syncthreads();

        #pragma unroll 4
        for (int k = 0; k < H_SZ; k += 4) {
            const float4 a0 = *(const float4*)&A[rg    ][k];  // LDS broadcast
            const float4 a1 = *(const float4*)&A[rg + 2][k];
            const float4 a2 = *(const float4*)&A[rg + 4][k];
            const float4 a3 = *(const float4*)&A[rg + 6][k];
            const float* Wp = W + (size_t)(kb + k) * H_SZ + c;
            const float w0 = Wp[0];
            const float w1 = Wp[H_SZ];
            const float w2 = Wp[2 * H_SZ];
            const float w3 = Wp[3 * H_SZ];
            acc[0] += a0.x * w0 + a0.y * w1 + a0.z * w2 + a0.w * w3;
            acc[1] += a1.x * w0 + a1.y * w1 + a1.z * w2 + a1.w * w3;
            acc[2] += a2.x * w0 + a2.y * w1 + a2.z * w2 + a2.w * w3;
            acc[3] += a3.x * w0 + a3.y * w1 + a3.z * w2 + a3.w * w3;
        }
    }

    // bias applies everywhere (matches nn.Linear on zeroed rows): b * sum(w_l)
    float sumw = 0.f;
    #pragma unroll
    for (int l = 0; l < L_SZ; ++l) sumw += 1.0f / log2f((float)(l + 2));
    const float bterm = bproj[c] * sumw;
    #pragma unroll
    for (int ri = 0; ri < 4; ++ri) e[rg + 2 * ri][c] = acc[ri] + bterm;

    if (tid < H_SZ) {
        const int uid = user_id[b];
        pref[tid] = pref_in[(size_t)b * H_SZ + tid]
                  + user_emb[(size_t)uid * H_SZ + tid];
    }
    __syncthreads();

    // wgts_org[k] = dot(e[k], pref): 8 groups of 32 lanes
    {
        const int k    = tid >> 5;
        const int lane = tid & 31;
        float s = e[k][lane]      * pref[lane]
                + e[k][lane + 32] * pref[lane + 32]
                + e[k][lane + 64] * pref[lane + 64]
                + e[k][lane + 96] * pref[lane + 96];
        #pragma unroll
        for (int m = 16; m >= 1; m >>= 1) s += __shfl_xor(s, m, 64);
        if (lane == 0) sdot[k] = s;
    }
    __syncthreads();

    if (tid == 0) {
        float mx = sdot[0];
        #pragma unroll
        for (int k = 1; k < K_SZ; ++k) mx = fmaxf(mx, sdot[k]);
        float sum = 0.f;
        float ex[K_SZ];
        #pragma unroll
        for (int k = 0; k < K_SZ; ++k) { ex[k] = expf(sdot[k] - mx); sum += ex[k]; }
        float ps = 0.f, ns = 0.f;
        #pragma unroll
        for (int k = 0; k < K_SZ; ++k) {
            const float w = ex[k] / sum;
            wg[k] = w;
            ps += pos_label[(size_t)b * K_SZ + k] * w;
            ns += neg_label[(size_t)b * K_SZ + k] * w;
        }
        const float x = ps - ns;
        lossb_s = fmaxf(-x, 0.f) + log1pf(expf(-fabsf(x)));   // softplus(-x)
    }
    __syncthreads();

    // diversity: sum_{i!=j} dot(e_i,e_j)^2 * (w_i + w_j)
    if (tid < 64) {
        const int i = tid >> 3;
        const int j = tid & 7;
        float g = 0.f;
        for (int h = 0; h < H_SZ; ++h) g += e[i][h] * e[j][h];
        float v = (i != j) ? (g * g * (wg[i] + wg[j])) : 0.f;
        #pragma unroll
        for (int m = 32; m >= 1; m >>= 1) v += __shfl_xor(v, m, 64);
        if (tid == 0) {
            const float mean_div = v / (float)(B_SZ * K_SZ * K_SZ);
            atomicAdd(out, lossb_s + DIV_TRADEOFF * mean_div);
        }
    }
}

// ---------------- Fallback path (round-1 kernels) if ws too small -----------
__global__ __launch_bounds__(256) void k_embed_fb(
    const int* __restrict__ preds, const float* __restrict__ item,
    const float* __restrict__ W, const float* __restrict__ bproj,
    float* __restrict__ emb)
{
    const int bk  = blockIdx.x;
    const int tid = threadIdx.x;
    __shared__ float wfs[DLLM];
    __shared__ float part[256];
    const int* p = preds + (size_t)bk * L_SZ;
    float a0 = 0.f, a1 = 0.f, a2 = 0.f;
    for (int l = 0; l < L_SZ; ++l) {
        const int id = p[l];
        if (id > 0 && id <= N_ITEM) {
            const float w = 1.0f / log2f((float)(l + 2));
            const float* row = item + (size_t)id * DLLM;
            a0 += w * row[tid];
            a1 += w * row[tid + 256];
            a2 += w * row[tid + 512];
        }
    }
    wfs[tid] = a0; wfs[tid + 256] = a1; wfs[tid + 512] = a2;
    __syncthreads();
    const int h = tid & (H_SZ - 1);
    const int half = tid >> 7;
    const float* Wc = W + h;
    float s = 0.f;
    const int d0 = half * 384;
    #pragma unroll 4
    for (int d = d0; d < d0 + 384; ++d) s += wfs[d] * Wc[(size_t)d * H_SZ];
    part[tid] = s;
    __syncthreads();
    if (tid < H_SZ) {
        float sumw = 0.f;
        for (int l = 0; l < L_SZ; ++l) sumw += 1.0f / log2f((float)(l + 2));
        emb[(size_t)bk * H_SZ + tid] = part[tid] + part[tid + H_SZ] + bproj[tid] * sumw;
    }
}

__global__ __launch_bounds__(256) void k_loss_fb(
    const int* __restrict__ user_id, const float* __restrict__ pref_in,
    const float* __restrict__ pos_label, const float* __restrict__ neg_label,
    const float* __restrict__ user_emb, const float* __restrict__ emb,
    float* __restrict__ out)
{
    const int b = blockIdx.x;
    const int tid = threadIdx.x;
    __shared__ float pref[H_SZ];
    __shared__ float e[K_SZ][H_SZ + 1];
    __shared__ float sdot[K_SZ];
    __shared__ float wg[K_SZ];
    __shared__ float lossb_s;
    if (tid < H_SZ) {
        const int uid = user_id[b];
        pref[tid] = pref_in[(size_t)b * H_SZ + tid] + user_emb[(size_t)uid * H_SZ + tid];
    }
    const float* eb = emb + (size_t)b * K_SZ * H_SZ;
    #pragma unroll
    for (int i = 0; i < 4; ++i) {
        const int idx = tid * 4 + i;
        e[idx >> 7][idx & (H_SZ - 1)] = eb[idx];
    }
    __syncthreads();
    {
        const int k = tid >> 5;
        const int lane = tid & 31;
        float s = e[k][lane] * pref[lane] + e[k][lane + 32] * pref[lane + 32]
                + e[k][lane + 64] * pref[lane + 64] + e[k][lane + 96] * pref[lane + 96];
        #pragma unroll
        for (int m = 16; m >= 1; m >>= 1) s += __shfl_xor(s, m, 64);
        if (lane == 0) sdot[k] = s;
    }
    __syncthreads();
    if (tid == 0) {
        float mx = sdot[0];
        #pragma unroll
        for (int k = 1; k < K_SZ; ++k) mx = fmaxf(mx, sdot[k]);
        float sum = 0.f; float ex[K_SZ];
        #pragma unroll
        for (int k = 0; k < K_SZ; ++k) { ex[k] = expf(sdot[k] - mx); sum += ex[k]; }
        float ps = 0.f, ns = 0.f;
        #pragma unroll
        for (int k = 0; k < K_SZ; ++k) {
            const float w = ex[k] / sum;
            wg[k] = w;
            ps += pos_label[(size_t)b * K_SZ + k] * w;
            ns += neg_label[(size_t)b * K_SZ + k] * w;
        }
        const float x = ps - ns;
        lossb_s = fmaxf(-x, 0.f) + log1pf(expf(-fabsf(x)));
    }
    __syncthreads();
    if (tid < 64) {
        const int i = tid >> 3;
        const int j = tid & 7;
        float g = 0.f;
        for (int h = 0; h < H_SZ; ++h) g += e[i][h] * e[j][h];
        float v = (i != j) ? (g * g * (wg[i] + wg[j])) : 0.f;
        #pragma unroll
        for (int m = 32; m >= 1; m >>= 1) v += __shfl_xor(v, m, 64);
        if (tid == 0) {
            const float mean_div = v / (float)(B_SZ * K_SZ * K_SZ);
            atomicAdd(out, lossb_s + DIV_TRADEOFF * mean_div);
        }
    }
}

extern "C" void kernel_launch(void* const* d_in, const int* in_sizes, int n_in,
                              void* d_out, int out_size, void* d_ws, size_t ws_size,
                              hipStream_t stream) {
    const int*   user_id   = (const int*)  d_in[0];
    const int*   preds     = (const int*)  d_in[1];
    const float* pref_in   = (const float*)d_in[2];
    const float* pos_label = (const float*)d_in[3];
    const float* neg_label = (const float*)d_in[4];
    const float* user_emb  = (const float*)d_in[5];
    const float* item_emb  = (const float*)d_in[6];
    const float* W_proj    = (const float*)d_in[7];
    const float* b_proj    = (const float*)d_in[8];

    float* out = (float*)d_out;

    const size_t wf_bytes = (size_t)B_SZ * K_SZ * DLLM * sizeof(float); // 12.6 MB

    if (ws_size >= wf_bytes) {
        float* wf = (float*)d_ws;
        k_gather<<<B_SZ * K_SZ, 192, 0, stream>>>(preds, item_emb, wf, out);
        k_projloss<<<B_SZ, 256, 0, stream>>>(wf, W_proj, b_proj, user_id, pref_in,
                                             pos_label, neg_label, user_emb, out);
    } else {
        hipMemsetAsync(out, 0, sizeof(float), stream);
        float* emb = (float*)d_ws;   // 2 MB
        k_embed_fb<<<B_SZ * K_SZ, 256, 0, stream>>>(preds, item_emb, W_proj, b_proj, emb);
        k_loss_fb<<<B_SZ, 256, 0, stream>>>(user_id, pref_in, pos_label, neg_label,
                                            user_emb, emb, out);
    }
}